// Round 17
// baseline (658.984 us; speedup 1.0000x reference)
//
#include <hip/hip_runtime.h>
#include <hip/hip_bf16.h>
#include <math.h>

#define B_    2
#define S_    8192
#define D_    1024
#define H_N   8
#define DK_   64
#define DV_   64
#define DH_   4096
#define SEG_  2048
#define NSEG_ 4
#define EPS_  1e-5f
#define LDQKV 1536

typedef __hip_bfloat16 bf16;
typedef unsigned int u32;
typedef __attribute__((ext_vector_type(8))) short bf16x8;
typedef __attribute__((ext_vector_type(4))) float f32x4;

union bvec { bf16x8 v; bf16 e[8]; };

template <typename T> __device__ inline T from_f(float v);
template <> __device__ inline float from_f<float>(float v) { return v; }
template <> __device__ inline bf16  from_f<bf16>(float v)  { return __float2bfloat16(v); }

__device__ __forceinline__ void gld_lds16(const bf16* g, bf16* l) {
    __builtin_amdgcn_global_load_lds(
        (const __attribute__((address_space(1))) u32*)g,
        (__attribute__((address_space(3))) u32*)l, 16, 0, 0);
}

__device__ inline float elu1(float x) { return x > 0.f ? x + 1.f : __expf(x); }

#define VMC(N) asm volatile("s_waitcnt vmcnt(" #N ")" ::: "memory")

// ---------------------------------------------------------------------------
// 256x256-tile GEMM (round-8/16 benched best — byte-identical, used for W1/W2)
// ---------------------------------------------------------------------------
#define GP(APTR, BPTR, MH, LOADB)                                              \
    {                                                                          \
        if (LOADB) {                                                           \
            _Pragma("unroll")                                                  \
            for (int n = 0; n < 4; n++)                                        \
                bg[n] = *(const bf16x8*)((BPTR) + n * 2048);                   \
        }                                                                      \
        _Pragma("unroll")                                                      \
        for (int m = 0; m < 4; m++)                                            \
            af[m] = *(const bf16x8*)((APTR) + (MH) * 8192 + m * 2048);         \
        asm volatile("s_waitcnt lgkmcnt(0)" ::: "memory");                     \
        __builtin_amdgcn_sched_barrier(0);                                     \
        __builtin_amdgcn_s_setprio(1);                                         \
        _Pragma("unroll")                                                      \
        for (int m = 0; m < 4; m++)                                            \
            _Pragma("unroll")                                                  \
            for (int n = 0; n < 4; n++)                                        \
                acc[(MH) * 4 + m][n] = __builtin_amdgcn_mfma_f32_16x16x32_bf16(\
                    af[m], bg[n], acc[(MH) * 4 + m][n], 0, 0, 0);              \
        __builtin_amdgcn_s_setprio(0);                                         \
    }

template <int EPI, typename CT>
__global__ __launch_bounds__(512, 1) void gemm256(
    const bf16* __restrict__ A, const bf16* __restrict__ BT, CT* __restrict__ C,
    const float* __restrict__ bias, const float* __restrict__ resid,
    int M, int N, int K)
{
    __shared__ bf16 L0[32768];
    __shared__ bf16 L1[32768];
    const int t    = threadIdx.x;
    const int lane = t & 63;
    const int w    = t >> 6;
    const int la   = lane & 15;
    const int g    = lane >> 4;

    const int nx  = gridDim.x;
    const int nwg = nx * gridDim.y;
    const int lin = blockIdx.y * nx + blockIdx.x;
    const int swzb = (lin & 7) * (nwg >> 3) + (lin >> 3);
    const int by  = swzb / nx, bx = swzb - by * nx;

    const int m0 = by * 256, n0 = bx * 256;
    const int wm = w >> 2, wn = w & 3;

    f32x4 acc[8][4];
    #pragma unroll
    for (int m = 0; m < 8; m++)
        #pragma unroll
        for (int n = 0; n < 4; n++) {
            f32x4 z4 = {0.f, 0.f, 0.f, 0.f};
            acc[m][n] = z4;
        }

    const int nt = K >> 6;

    const int rq = w * 8 + (lane >> 3);
    const int c8 = ((lane & 7) ^ (lane >> 3)) * 8;
    auto stageQ = [&](int kt_, int q, bf16* Lb) {
        const size_t k0 = (size_t)kt_ << 6;
        gld_lds16(A  + (size_t)(m0 + q * 64 + rq) * K + k0 + c8,
                  Lb + q * 4096 + w * 512);
        gld_lds16(BT + (size_t)(n0 + q * 64 + rq) * K + k0 + c8,
                  Lb + 16384 + q * 4096 + w * 512);
    };

    const int sw0 = (g ^ (la & 7)) << 4;
    const int sw1 = ((4 + g) ^ (la & 7)) << 4;
    const int aoff = (wm * 128 + la) * 128;
    const int boff = 32768 + (wn * 64 + la) * 128;
    const char* a0k0 = (const char*)L0 + aoff + sw0;
    const char* a0k1 = (const char*)L0 + aoff + sw1;
    const char* b0k0 = (const char*)L0 + boff + sw0;
    const char* b0k1 = (const char*)L0 + boff + sw1;
    const char* a1k0 = (const char*)L1 + aoff + sw0;
    const char* a1k1 = (const char*)L1 + aoff + sw1;
    const char* b1k0 = (const char*)L1 + boff + sw0;
    const char* b1k1 = (const char*)L1 + boff + sw1;

    stageQ(0, 0, L0); stageQ(0, 1, L0); stageQ(0, 2, L0); stageQ(0, 3, L0);

    bf16x8 af[4], bg[4];
    for (int tt = 0; tt < nt; tt += 2) {
        const bool more = (tt + 2 < nt);
        __builtin_amdgcn_s_barrier();
        stageQ(tt + 1, 0, L1);
        asm volatile("s_waitcnt vmcnt(2)" ::: "memory");
        __builtin_amdgcn_sched_barrier(0);
        __builtin_amdgcn_s_barrier();
        GP(a0k0, b0k0, 0, true);
        __builtin_amdgcn_s_barrier();
        stageQ(tt + 1, 1, L1);
        GP(a0k0, b0k0, 1, false);
        __builtin_amdgcn_s_barrier();
        stageQ(tt + 1, 2, L1);
        GP(a0k1, b0k1, 0, true);
        __builtin_amdgcn_s_barrier();
        stageQ(tt + 1, 3, L1);
        GP(a0k1, b0k1, 1, false);
        __builtin_amdgcn_s_barrier();
        if (more) {
            stageQ(tt + 2, 0, L0);
            asm volatile("s_waitcnt vmcnt(2)" ::: "memory");
        } else {
            asm volatile("s_waitcnt vmcnt(0)" ::: "memory");
        }
        __builtin_amdgcn_sched_barrier(0);
        __builtin_amdgcn_s_barrier();
        GP(a1k0, b1k0, 0, true);
        __builtin_amdgcn_s_barrier();
        if (more) stageQ(tt + 2, 1, L0);
        GP(a1k0, b1k0, 1, false);
        __builtin_amdgcn_s_barrier();
        if (more) stageQ(tt + 2, 2, L0);
        GP(a1k1, b1k1, 0, true);
        __builtin_amdgcn_s_barrier();
        if (more) stageQ(tt + 2, 3, L0);
        GP(a1k1, b1k1, 1, false);
    }

    const int row0 = m0 + wm * 128 + g * 4;
    const int col0 = n0 + wn * 64 + la;
    float bj[4];
    if (EPI >= 2) {
        #pragma unroll
        for (int n = 0; n < 4; n++) bj[n] = bias[col0 + n * 16];
    }
    #pragma unroll
    for (int m = 0; m < 8; m++) {
        #pragma unroll
        for (int r = 0; r < 4; r++) {
            const int row = row0 + m * 16 + r;
            #pragma unroll
            for (int n = 0; n < 4; n++) {
                const int col = col0 + n * 16;
                float v = acc[m][n][r];
                if (EPI >= 2) v += bj[n];
                if (EPI == 2) v = 0.5f * v * (1.0f + erff(v * 0.70710678118654752f));
                if (EPI == 3) v += resid[(size_t)row * N + col];
                C[(size_t)row * N + col] = from_f<CT>(v);
            }
        }
    }
}

// ---------------------------------------------------------------------------
// 128x128-tile GEMM (round-10/16 benched) — short-K GEMMs (QKV, Wo)
// ---------------------------------------------------------------------------
template <int EPI, typename CT>
__global__ __launch_bounds__(256, 4) void gemm128(
    const bf16* __restrict__ A, const bf16* __restrict__ BT, CT* __restrict__ C,
    const float* __restrict__ bias, const float* __restrict__ resid,
    int M, int N, int K)
{
    __shared__ bf16 L0[8192];
    __shared__ bf16 L1[8192];
    const int t    = threadIdx.x;
    const int lane = t & 63;
    const int w    = t >> 6;
    const int la   = lane & 15;
    const int g    = lane >> 4;

    const int nx  = gridDim.x;
    const int nwg = nx * gridDim.y;
    const int lin = blockIdx.y * nx + blockIdx.x;
    const int swzb = (lin & 7) * (nwg >> 3) + (lin >> 3);
    const int by  = swzb / nx, bx = swzb - by * nx;

    const int m0 = by * 128, n0 = bx * 128;
    const int wm = w >> 1, wn = w & 1;

    f32x4 acc[4][4];
    #pragma unroll
    for (int m = 0; m < 4; m++)
        #pragma unroll
        for (int n = 0; n < 4; n++) {
            f32x4 z4 = {0.f, 0.f, 0.f, 0.f};
            acc[m][n] = z4;
        }

    const int nt = K >> 5;

    const int r16 = lane >> 2;
    const int c4  = ((lane & 3) ^ ((lane >> 3) & 3)) * 8;
    auto stage = [&](int kt_, bf16* Lb) {
        const size_t k0 = (size_t)kt_ << 5;
        #pragma unroll
        for (int j = 0; j < 2; j++) {
            const int row = (j * 4 + w) * 16 + r16;
            gld_lds16(A  + (size_t)(m0 + row) * K + k0 + c4,
                      Lb + (j * 4 + w) * 512);
            gld_lds16(BT + (size_t)(n0 + row) * K + k0 + c4,
                      Lb + 4096 + (j * 4 + w) * 512);
        }
    };

    const int swz = ((g ^ ((la >> 1) & 3)) << 4);
    const char* bA0 = (const char*)L0 + (wm * 64 + la) * 64 + swz;
    const char* bB0 = (const char*)L0 + 8192 + (wn * 64 + la) * 64 + swz;
    const char* bA1 = (const char*)L1 + (wm * 64 + la) * 64 + swz;
    const char* bB1 = (const char*)L1 + 8192 + (wn * 64 + la) * 64 + swz;

    auto comp = [&](const char* bA, const char* bB) {
        bf16x8 af[4], bg[4];
        #pragma unroll
        for (int n = 0; n < 4; n++) bg[n] = *(const bf16x8*)(bB + n * 1024);
        #pragma unroll
        for (int m = 0; m < 4; m++) af[m] = *(const bf16x8*)(bA + m * 1024);
        #pragma unroll
        for (int m = 0; m < 4; m++)
            #pragma unroll
            for (int n = 0; n < 4; n++)
                acc[m][n] = __builtin_amdgcn_mfma_f32_16x16x32_bf16(
                    af[m], bg[n], acc[m][n], 0, 0, 0);
    };

    stage(0, L0);
    VMC(0);
    __builtin_amdgcn_sched_barrier(0);
    __builtin_amdgcn_s_barrier();

    for (int tt = 0; tt < nt; tt += 2) {
        const bool more = (tt + 2 < nt);
        stage(tt + 1, L1);
        comp(bA0, bB0);
        VMC(0);
        __builtin_amdgcn_sched_barrier(0);
        __builtin_amdgcn_s_barrier();
        if (more) stage(tt + 2, L0);
        comp(bA1, bB1);
        if (more) {
            VMC(0);
            __builtin_amdgcn_sched_barrier(0);
            __builtin_amdgcn_s_barrier();
        }
    }

    const int row0 = m0 + wm * 64 + g * 4;
    const int col0 = n0 + wn * 64 + la;
    float bj[4];
    if (EPI >= 2) {
        #pragma unroll
        for (int n = 0; n < 4; n++) bj[n] = bias[col0 + n * 16];
    }
    #pragma unroll
    for (int m = 0; m < 4; m++) {
        #pragma unroll
        for (int r = 0; r < 4; r++) {
            const int row = row0 + m * 16 + r;
            #pragma unroll
            for (int n = 0; n < 4; n++) {
                const int col = col0 + n * 16;
                float v = acc[m][n][r];
                if (EPI >= 2) v += bj[n];
                if (EPI == 2) v = 0.5f * v * (1.0f + erff(v * 0.70710678118654752f));
                if (EPI == 3) v += resid[(size_t)row * N + col];
                C[(size_t)row * N + col] = from_f<CT>(v);
            }
        }
    }
}

// ---------------------------------------------------------------------------
// Fused prologue: x->bf16 cast AND all weight transpose-casts in ONE launch.
// blocks [0,16384): castx (1024 f32 each)
// blocks [16384,16384+10240): transpose-cast tiles
//   [0,1536)=Wq/Wk/Wv  [1536,2048)=Wo  [2048,6144)=W1  [6144,10240)=W2
// ---------------------------------------------------------------------------
__global__ __launch_bounds__(256) void prep_k(
    const float* __restrict__ X, bf16* __restrict__ Xb,
    const float* __restrict__ Wq, const float* __restrict__ Wk,
    const float* __restrict__ Wv, const float* __restrict__ Wo,
    const float* __restrict__ W1, const float* __restrict__ W2,
    bf16* __restrict__ WqkvT, bf16* __restrict__ WoT,
    bf16* __restrict__ W1T, bf16* __restrict__ W2T)
{
    const int fb0 = blockIdx.x;
    if (fb0 < 16384) {
        size_t i = ((size_t)fb0 * 256 + threadIdx.x) * 4;
        float4 v = *(const float4*)(X + i);
        union { bf16 b[4]; unsigned long long u; } o;
        o.b[0] = __float2bfloat16(v.x);
        o.b[1] = __float2bfloat16(v.y);
        o.b[2] = __float2bfloat16(v.z);
        o.b[3] = __float2bfloat16(v.w);
        *(unsigned long long*)(Xb + i) = o.u;
        return;
    }
    __shared__ float tile[32][33];
    const int fb = fb0 - 16384;
    const float* W; bf16* WT; int K, N, n0, k0;
    if (fb < 1536) {
        const int z = fb / 512, idx = fb - z * 512;
        W  = (z == 0) ? Wq : (z == 1) ? Wk : Wv;
        WT = WqkvT + (size_t)z * 512 * 1024;
        K = 1024; N = 512;
        n0 = (idx & 15) * 32; k0 = (idx >> 4) * 32;
    } else if (fb < 2048) {
        const int idx = fb - 1536;
        W = Wo; WT = WoT; K = 512; N = 1024;
        n0 = (idx & 31) * 32; k0 = (idx >> 5) * 32;
    } else if (fb < 6144) {
        const int idx = fb - 2048;
        W = W1; WT = W1T; K = 1024; N = 4096;
        n0 = (idx & 127) * 32; k0 = (idx >> 7) * 32;
    } else {
        const int idx = fb - 6144;
        W = W2; WT = W2T; K = 4096; N = 1024;
        n0 = (idx & 31) * 32; k0 = (idx >> 5) * 32;
    }
    const int tx = threadIdx.x & 31, ty = threadIdx.x >> 5;
    #pragma unroll
    for (int i = 0; i < 32; i += 8)
        tile[ty + i][tx] = W[(size_t)(k0 + ty + i) * N + n0 + tx];
    __syncthreads();
    #pragma unroll
    for (int i = 0; i < 32; i += 8)
        WT[(size_t)(n0 + ty + i) * K + k0 + tx] = __float2bfloat16(tile[tx][ty + i]);
}

// V (stride LDQKV) -> Vt [ (b*8+h)*64+dv ][ s ]
__global__ __launch_bounds__(256) void vtrans_k(const bf16* __restrict__ V,
                                                bf16* __restrict__ Vt)
{
    __shared__ bf16 t_[64 * 64];
    const int t = threadIdx.x;
    const int sblk = blockIdx.x & 127;
    const int b = blockIdx.x >> 7;
    const int h = blockIdx.y;
    const bf16* src = V + ((size_t)b * S_ + sblk * 64) * LDQKV + h * 64;
    #pragma unroll
    for (int k = 0; k < 2; k++) {
        int e = t + k * 256;
        int r = e >> 3, c8 = (e & 7) * 8;
        *(bf16x8*)&t_[r * 64 + c8] = *(const bf16x8*)&src[(size_t)r * LDQKV + c8];
    }
    __syncthreads();
    const int dv = t & 63, s0 = (t >> 6) * 16;
    bf16* dst = Vt + ((size_t)(b * 8 + h) * 64 + dv) * (size_t)S_ + sblk * 64 + s0;
    bvec o0, o1;
    #pragma unroll
    for (int i = 0; i < 8; i++) {
        o0.e[i] = t_[(s0 + i) * 64 + dv];
        o1.e[i] = t_[(s0 + 8 + i) * 64 + dv];
    }
    *(bf16x8*)dst = o0.v;
    *(bf16x8*)(dst + 8) = o1.v;
}

// ---------------------------------------------------------------------------
// Per-(segment, 1/16-chunk) partial memory; grid (NSEG_*16, 16)
// ---------------------------------------------------------------------------
__global__ __launch_bounds__(256) void memseg_k(
    const bf16* __restrict__ Kg, const bf16* __restrict__ Vg,
    float* __restrict__ MP, float* __restrict__ ZP)
{
    __shared__ float Ks[64][65];
    __shared__ float Vs[64][65];
    const int t = threadIdx.x, tx = t & 15, ty = t >> 4;
    const int sb = blockIdx.x;
    const int seg = sb >> 4, bh = sb & 15;
    const int b = bh >> 3, h = bh & 7;
    const int chunk = blockIdx.y;
    const size_t base = ((size_t)b * S_ + (size_t)seg * SEG_ + (size_t)chunk * 128) * LDQKV + h * 64;

    float acc[4][4] = {};
    float zacc[4]   = {};
    for (int st = 0; st < 2; st++) {
        #pragma unroll
        for (int kk = 0; kk < 2; kk++) {
            int e = t + kk * 256;
            int r = e >> 3, c8 = (e & 7) * 8;
            size_t go = base + ((size_t)st * 64 + r) * LDQKV + c8;
            bvec kv_, vv_;
            kv_.v = *(const bf16x8*)&Kg[go];
            vv_.v = *(const bf16x8*)&Vg[go];
            #pragma unroll
            for (int i = 0; i < 8; i++) {
                Ks[r][c8 + i] = elu1(__bfloat162float(kv_.e[i]));
                Vs[r][c8 + i] = __bfloat162float(vv_.e[i]);
            }
        }
        __syncthreads();
        for (int s = 0; s < 64; s++) {
            float a4[4], v4[4];
            #pragma unroll
            for (int i = 0; i < 4; i++) a4[i] = Ks[s][ty * 4 + i];
            #pragma unroll
            for (int j = 0; j < 4; j++) v4[j] = Vs[s][tx * 4 + j];
            #pragma unroll
            for (int i = 0; i < 4; i++)
                #pragma unroll
                for (int j = 0; j < 4; j++)
                    acc[i][j] += a4[i] * v4[j];
        }
        #pragma unroll
        for (int ii = 0; ii < 4; ii++) {
            int s = tx + ii * 16;
            #pragma unroll
            for (int i = 0; i < 4; i++) zacc[i] += Ks[s][ty * 4 + i];
        }
        __syncthreads();
    }
    const int slot = (seg * 16 + chunk) * 16 + bh;
    #pragma unroll
    for (int i = 0; i < 4; i++)
        #pragma unroll
        for (int j = 0; j < 4; j++)
            MP[(size_t)slot * 4096 + (ty * 4 + i) * 64 + tx * 4 + j] = acc[i][j];
    #pragma unroll
    for (int i = 0; i < 4; i++) {
        float zz = zacc[i];
        #pragma unroll
        for (int mk = 1; mk < 16; mk <<= 1) zz += __shfl_xor(zz, mk);
        if (tx == 0) ZP[slot * 64 + ty * 4 + i] = zz;
    }
}

// exclusive prefix over 64 (seg,chunk) slots; grid (16 bh, 16 e-groups)
__global__ __launch_bounds__(256) void prefix_k(
    const float* __restrict__ MP, const float* __restrict__ ZP,
    bf16* __restrict__ MST, float* __restrict__ ZS)
{
    const int bh = blockIdx.x;
    const int e  = blockIdx.y * 256 + threadIdx.x;
    const int dk = e >> 6, dv = e & 63;
    float s = 0.f;
    for (int si = 0; si < 64; si++) {
        if ((si & 15) == 0)
            MST[(size_t)((si >> 4) * 16 + bh) * 4096 + dv * 64 + dk] = __float2bfloat16(s);
        s += MP[(size_t)(si * 16 + bh) * 4096 + e];
    }
    if (blockIdx.y == 0 && threadIdx.x < 64) {
        const int dz = threadIdx.x;
        float z = 1.0f / DK_;
        for (int si = 0; si < 64; si++) {
            if ((si & 15) == 0) ZS[((si >> 4) * 16 + bh) * 64 + dz] = z;
            z += ZP[(si * 16 + bh) * 64 + dz];
        }
    }
}

// ---------------------------------------------------------------------------
// attn helpers
// ---------------------------------------------------------------------------
template <int NG>
__device__ __forceinline__ void stageT(const bf16* gsrc, size_t stride, bf16* lds,
                                       int wave, int lane)
{
    #pragma unroll
    for (int ii = 0; ii < NG; ii++) {
        int i = wave * NG + ii;
        gld_lds16(gsrc + (size_t)(8 * i + (lane >> 3)) * stride
                        + (size_t)(((lane & 7) ^ (lane >> 3)) * 8),
                  lds + i * 512);
    }
}

__device__ __forceinline__ bf16x8 ldsw128(const bf16* base, int row, int colE)
{
    int off = row * 128 + ((colE * 2) ^ ((row & 7) << 4));
    return *(const bf16x8*)((const char*)base + off);
}

// ---------------------------------------------------------------------------
// MFMA flash attention (round-16 benched + T5 setprio on MFMA clusters)
// ---------------------------------------------------------------------------
__global__ __launch_bounds__(256) void attn_k(
    const bf16* __restrict__ Qg, const bf16* __restrict__ Kg, const bf16* __restrict__ Vt,
    const bf16* __restrict__ MsT, const float* __restrict__ ZS,
    const float* __restrict__ betas, bf16* __restrict__ att)
{
    __shared__ bf16 KT[2][4096];
    __shared__ bf16 VTs[2][4096];
    __shared__ bf16 QP[8192];
    __shared__ float Zsm[64];

    const int t    = threadIdx.x;
    const int lane = t & 63;
    const int w    = t >> 6;
    const int la   = lane & 15;
    const int g    = lane >> 4;
    const int qt   = (int)gridDim.x - 1 - (int)blockIdx.x;
    const int bh   = blockIdx.y;
    const int seg  = blockIdx.z;
    const int b    = bh >> 3, h = bh & 7;

    const size_t srow = (size_t)b * S_ + (size_t)seg * SEG_;
    const bf16* qp  = Qg + (srow + (size_t)qt * 128) * LDQKV + h * 64;
    const bf16* kp  = Kg + srow * LDQKV + h * 64;
    const bf16* vtp = Vt + (size_t)bh * 64 * (size_t)S_ + (size_t)seg * SEG_;

    stageT<4>(qp, LDQKV, QP, w, lane);
    stageT<2>(kp, LDQKV, KT[0], w, lane);
    stageT<2>(vtp, S_, VTs[0], w, lane);
    if (t < 64) Zsm[t] = ZS[(seg * 16 + bh) * 64 + t];
    __syncthreads();

    bf16x8 aq[2][2];
    #pragma unroll
    for (int st = 0; st < 2; st++)
        #pragma unroll
        for (int s = 0; s < 2; s++)
            aq[st][s] = ldsw128(QP, w * 32 + st * 16 + la, s * 32 + g * 8);

    float m_[2] = {-1e30f, -1e30f};
    float l_[2] = {0.f, 0.f};
    f32x4 Oa[2][4];
    #pragma unroll
    for (int st = 0; st < 2; st++)
        #pragma unroll
        for (int j = 0; j < 4; j++) { f32x4 z4 = {0.f,0.f,0.f,0.f}; Oa[st][j] = z4; }

    const int jtmax = 2 * qt + 1;
    int cur = 0;
    for (int jt = 0; jt <= jtmax; jt++, cur ^= 1) {
        if (jt < jtmax) {
            stageT<2>(kp + (size_t)(jt + 1) * 64 * LDQKV, LDQKV, KT[cur ^ 1], w, lane);
            stageT<2>(vtp + (size_t)(jt + 1) * 64, S_, VTs[cur ^ 1], w, lane);
        }

        bf16x8 kf[2][4];
        #pragma unroll
        for (int s = 0; s < 2; s++)
            #pragma unroll
            for (int j = 0; j < 4; j++)
                kf[s][j] = ldsw128(KT[cur], j * 16 + la, s * 32 + g * 8);

        const int jtkv = jt * 64;
        #pragma unroll
        for (int st = 0; st < 2; st++) {
            f32x4 sc[4];
            #pragma unroll
            for (int j = 0; j < 4; j++) { f32x4 z4 = {0.f,0.f,0.f,0.f}; sc[j] = z4; }
            __builtin_amdgcn_s_setprio(1);
            #pragma unroll
            for (int j = 0; j < 4; j++) {
                sc[j] = __builtin_amdgcn_mfma_f32_16x16x32_bf16(kf[0][j], aq[st][0], sc[j], 0, 0, 0);
                sc[j] = __builtin_amdgcn_mfma_f32_16x16x32_bf16(kf[1][j], aq[st][1], sc[j], 0, 0, 0);
            }
            __builtin_amdgcn_s_setprio(0);

            const int q_abs = qt * 128 + w * 32 + st * 16 + la;
            float sv[4][4];
            float mx = -1e30f;
            #pragma unroll
            for (int j = 0; j < 4; j++)
                #pragma unroll
                for (int r = 0; r < 4; r++) {
                    float v = sc[j][r] * 0.125f;
                    int kv = jtkv + j * 16 + g * 4 + r;
                    v = (kv <= q_abs) ? v : -1e30f;
                    sv[j][r] = v;
                    mx = fmaxf(mx, v);
                }
            mx = fmaxf(mx, __shfl_xor(mx, 16));
            mx = fmaxf(mx, __shfl_xor(mx, 32));
            float mnew = fmaxf(m_[st], mx);
            float corr = __expf(m_[st] - mnew);
            float rs = 0.f;
            #pragma unroll
            for (int j = 0; j < 4; j++)
                #pragma unroll
                for (int r = 0; r < 4; r++) {
                    float p = __expf(sv[j][r] - mnew);
                    sv[j][r] = p;
                    rs += p;
                }
            rs += __shfl_xor(rs, 16);
            rs += __shfl_xor(rs, 32);
            l_[st] = l_[st] * corr + rs;
            m_[st] = mnew;

            const int R = w * 32 + st * 16 + la;
            #pragma unroll
            for (int j = 0; j < 4; j++) {
                union { bf16 e[4]; uint2 u; } pk;
                #pragma unroll
                for (int r = 0; r < 4; r++) pk.e[r] = __float2bfloat16(sv[j][r]);
                int off = R * 128 + ((j * 32 + g * 8) ^ ((la & 7) << 4));
                *(uint2*)((char*)QP + off) = pk.u;
            }

            #pragma unroll
            for (int r = 0; r < 4; r++) {
                float corr_r = __shfl(corr, (lane & 48) | (g * 4 + r));
                #pragma unroll
                for (int j = 0; j < 4; j++) Oa[st][j][r] *= corr_r;
            }
        }

        asm volatile("s_waitcnt lgkmcnt(0)" ::: "memory");
        __builtin_amdgcn_sched_barrier(0);

        bf16x8 bv[2][4];
        #pragma unroll
        for (int s = 0; s < 2; s++)
            #pragma unroll
            for (int j = 0; j < 4; j++)
                bv[s][j] = ldsw128(VTs[cur], j * 16 + la, s * 32 + g * 8);
        #pragma unroll
        for (int st = 0; st < 2; st++) {
            bf16x8 ap0 = ldsw128(QP, w * 32 + st * 16 + la, g * 8);
            bf16x8 ap1 = ldsw128(QP, w * 32 + st * 16 + la, 32 + g * 8);
            __builtin_amdgcn_s_setprio(1);
            #pragma unroll
            for (int j = 0; j < 4; j++) {
                Oa[st][j] = __builtin_amdgcn_mfma_f32_16x16x32_bf16(ap0, bv[0][j], Oa[st][j], 0, 0, 0);
                Oa[st][j] = __builtin_amdgcn_mfma_f32_16x16x32_bf16(ap1, bv[1][j], Oa[st][j], 0, 0, 0);
            }
            __builtin_amdgcn_s_setprio(0);
        }
        __syncthreads();
    }

    // ---- retrieval ----
    stageT<2>(MsT + (size_t)(seg * 16 + bh) * 4096, 64, KT[0], w, lane);
    __syncthreads();

    bf16x8 sq[2][2];
    float den[2] = {0.f, 0.f};
    #pragma unroll
    for (int st = 0; st < 2; st++) {
        #pragma unroll
        for (int s = 0; s < 2; s++) {
            bvec in, outv;
            in.v = aq[st][s];
            #pragma unroll
            for (int e = 0; e < 8; e++) {
                float f = elu1(__bfloat162float(in.e[e]));
                outv.e[e] = __float2bfloat16(f);
                den[st] += f * Zsm[s * 32 + 8 * g + e];
            }
            sq[st][s] = outv.v;
        }
        den[st] += __shfl_xor(den[st], 16);
        den[st] += __shfl_xor(den[st], 32);
    }

    bf16x8 bm[2][4];
    #pragma unroll
    for (int s = 0; s < 2; s++)
        #pragma unroll
        for (int j = 0; j < 4; j++)
            bm[s][j] = ldsw128(KT[0], j * 16 + la, s * 32 + g * 8);

    float gate[4];
    #pragma unroll
    for (int j = 0; j < 4; j++)
        gate[j] = 1.f / (1.f + __expf(-betas[h * 64 + j * 16 + la]));

    #pragma unroll
    for (int st = 0; st < 2; st++) {
        f32x4 num[4];
        #pragma unroll
        for (int j = 0; j < 4; j++) { f32x4 z4 = {0.f,0.f,0.f,0.f}; num[j] = z4; }
        __builtin_amdgcn_s_setprio(1);
        #pragma unroll
        for (int j = 0; j < 4; j++) {
            num[j] = __builtin_amdgcn_mfma_f32_16x16x32_bf16(sq[st][0], bm[0][j], num[j], 0, 0, 0);
            num[j] = __builtin_amdgcn_mfma_f32_16x16x32_bf16(sq[st][1], bm[1][j], num[j], 0, 0, 0);
        }
        __builtin_amdgcn_s_setprio(0);
        #pragma unroll
        for (int r = 0; r < 4; r++) {
            float den_r = __shfl(den[st], (lane & 48) | (g * 4 + r));
            float l_r   = __shfl(l_[st],  (lane & 48) | (g * 4 + r));
            float linv  = 1.f / l_r;
            float dinv  = 1.f / den_r;
            size_t orow = srow + (size_t)qt * 128 + w * 32 + st * 16 + g * 4 + r;
            #pragma unroll
            for (int j = 0; j < 4; j++) {
                float am = num[j][r] * dinv;
                float ad = Oa[st][j][r] * linv;
                att[orow * 512 + h * 64 + j * 16 + la] =
                    __float2bfloat16(gate[j] * am + (1.f - gate[j]) * ad);
            }
        }
    }
}

// ---------------------------------------------------------------------------
// LayerNorm reading bf16 y, f32 out
// ---------------------------------------------------------------------------
__global__ __launch_bounds__(256) void lnb_k(
    const bf16* __restrict__ Y, const float* __restrict__ g,
    const float* __restrict__ bta, float* __restrict__ out)
{
    const int row = blockIdx.x;
    const bf16* yp = Y + (size_t)row * D_;
    const int t = threadIdx.x;
    float v[4];
    float s = 0.f, s2 = 0.f;
    {
        union { bf16 e[4]; uint2 u; } ld;
        ld.u = *(const uint2*)(yp + t * 4);
        #pragma unroll
        for (int i = 0; i < 4; i++) {
            v[i] = __bfloat162float(ld.e[i]);
            s += v[i]; s2 += v[i] * v[i];
        }
    }
    #pragma unroll
    for (int mk = 1; mk < 64; mk <<= 1) {
        s  += __shfl_xor(s, mk);
        s2 += __shfl_xor(s2, mk);
    }
    __shared__ float ss[4], ss2[4];
    int w = t >> 6;
    if ((t & 63) == 0) { ss[w] = s; ss2[w] = s2; }
    __syncthreads();
    s  = ss[0] + ss[1] + ss[2] + ss[3];
    s2 = ss2[0] + ss2[1] + ss2[2] + ss2[3];
    float mu   = s / D_;
    float var  = s2 / D_ - mu * mu;
    float rstd = rsqrtf(var + EPS_);
    #pragma unroll
    for (int i = 0; i < 4; i++) {
        int c = t * 4 + i;
        out[(size_t)row * D_ + c] = (v[i] - mu) * rstd * g[c] + bta[c];
    }
}

// ---------------------------------------------------------------------------
extern "C" void kernel_launch(void* const* d_in, const int* in_sizes, int n_in,
                              void* d_out, int out_size, void* d_ws, size_t ws_size,
                              hipStream_t stream)
{
    const float* x     = (const float*)d_in[0];
    const float* Wq    = (const float*)d_in[1];
    const float* Wk    = (const float*)d_in[2];
    const float* Wv    = (const float*)d_in[3];
    const float* Wo    = (const float*)d_in[4];
    const float* betas = (const float*)d_in[5];
    const float* W1    = (const float*)d_in[6];
    const float* b1    = (const float*)d_in[7];
    const float* W2    = (const float*)d_in[8];
    const float* b2    = (const float*)d_in[9];
    const float* lng   = (const float*)d_in[10];
    const float* lnb   = (const float*)d_in[11];
    float* out = (float*)d_out;

    const int M = B_ * S_;                    // 16384
    char* base = (char*)d_ws;
    const size_t MB = 1024 * 1024;

    // Liveness-safe layout (round-13/16 benched):
    bf16*  Ab    = (bf16*)(base);
    bf16*  Yb    = (bf16*)(base);             // aliases Ab; Ab dead after W1
    bf16*  Hb    = (bf16*)(base + 32 * MB);
    bf16*  Xbf   = (bf16*)(base + 32 * MB);
    bf16*  QKV   = (bf16*)(base + 64 * MB);   // [M][1536]
    bf16*  Vt    = (bf16*)(base + 112 * MB);
    bf16*  ATT   = (bf16*)(base + 128 * MB);  // [M][512]
    bf16*  WqkvT = (bf16*)(base + 160 * MB);  // 3MB
    bf16*  WoT   = (bf16*)(base + 163 * MB);  // 1MB
    bf16*  W1T   = (bf16*)(base + 164 * MB);  // 8MB
    bf16*  W2T   = (bf16*)(base + 172 * MB);  // 8MB
    float* MP    = (float*)(base + 180 * MB); // 16MB (180-196)
    bf16*  MST   = (bf16*)(base + 196 * MB);  // 512KB
    float* ZP    = (float*)(base + 196 * MB + 512 * 1024);   // 256KB
    float* ZS    = (float*)(base + 196 * MB + 768 * 1024);

    dim3 blk(256);
    dim3 blk512(512);

    // fused prologue: castx + all weight transpose-casts
    prep_k<<<dim3(16384 + 10240), blk, 0, stream>>>(
        x, Xbf, Wq, Wk, Wv, Wo, W1, W2, WqkvT, WoT, W1T, W2T);

    // fused QKV projection (short K -> gemm128)
    gemm128<0, bf16><<<dim3(1536 / 128, M / 128), blk, 0, stream>>>(
        Xbf, WqkvT, QKV, nullptr, nullptr, M, 1536, 1024);

    vtrans_k<<<dim3(256, 8), blk, 0, stream>>>(QKV + 1024, Vt);

    memseg_k<<<dim3(NSEG_ * 16, 16), blk, 0, stream>>>(QKV + 512, QKV + 1024, MP, ZP);
    prefix_k<<<dim3(16, 16), blk, 0, stream>>>(MP, ZP, MST, ZS);

    attn_k<<<dim3(SEG_ / 128, 16, NSEG_), blk, 0, stream>>>(
        QKV, QKV + 512, Vt, MST, ZS, betas, ATT);

    // output projection (short K -> gemm128)
    gemm128<0, bf16><<<dim3(1024 / 128, M / 128), blk, 0, stream>>>(
        ATT, WoT, Ab, nullptr, nullptr, M, 1024, 512);
    // FFN (big K -> gemm256, benched best)
    gemm256<2, bf16><<<dim3(4096 / 256, M / 256), blk512, 0, stream>>>(
        Ab, W1T, Hb, b1, nullptr, M, 4096, 1024);
    gemm256<3, bf16><<<dim3(1024 / 256, M / 256), blk512, 0, stream>>>(
        Hb, W2T, Yb, b2, x, M, 1024, 4096);

    lnb_k<<<dim3(M), blk, 0, stream>>>(Yb, lng, lnb, out);
}

// Round 18
// 647.302 us; speedup vs baseline: 1.0180x; 1.0180x over previous
//
#include <hip/hip_runtime.h>
#include <hip/hip_bf16.h>
#include <math.h>

#define B_    2
#define S_    8192
#define D_    1024
#define H_N   8
#define DK_   64
#define DV_   64
#define DH_   4096
#define SEG_  2048
#define NSEG_ 4
#define EPS_  1e-5f
#define LDQKV 1536

typedef __hip_bfloat16 bf16;
typedef unsigned int u32;
typedef __attribute__((ext_vector_type(8))) short bf16x8;
typedef __attribute__((ext_vector_type(4))) float f32x4;

union bvec { bf16x8 v; bf16 e[8]; };

template <typename T> __device__ inline T from_f(float v);
template <> __device__ inline float from_f<float>(float v) { return v; }
template <> __device__ inline bf16  from_f<bf16>(float v)  { return __float2bfloat16(v); }

__device__ __forceinline__ void gld_lds16(const bf16* g, bf16* l) {
    __builtin_amdgcn_global_load_lds(
        (const __attribute__((address_space(1))) u32*)g,
        (__attribute__((address_space(3))) u32*)l, 16, 0, 0);
}

__device__ inline float elu1(float x) { return x > 0.f ? x + 1.f : __expf(x); }

#define VMC(N) asm volatile("s_waitcnt vmcnt(" #N ")" ::: "memory")

// ---------------------------------------------------------------------------
// 256x256-tile GEMM (round-8/16 benched best — byte-identical, used for W1/W2)
// ---------------------------------------------------------------------------
#define GP(APTR, BPTR, MH, LOADB)                                              \
    {                                                                          \
        if (LOADB) {                                                           \
            _Pragma("unroll")                                                  \
            for (int n = 0; n < 4; n++)                                        \
                bg[n] = *(const bf16x8*)((BPTR) + n * 2048);                   \
        }                                                                      \
        _Pragma("unroll")                                                      \
        for (int m = 0; m < 4; m++)                                            \
            af[m] = *(const bf16x8*)((APTR) + (MH) * 8192 + m * 2048);         \
        asm volatile("s_waitcnt lgkmcnt(0)" ::: "memory");                     \
        __builtin_amdgcn_sched_barrier(0);                                     \
        __builtin_amdgcn_s_setprio(1);                                         \
        _Pragma("unroll")                                                      \
        for (int m = 0; m < 4; m++)                                            \
            _Pragma("unroll")                                                  \
            for (int n = 0; n < 4; n++)                                        \
                acc[(MH) * 4 + m][n] = __builtin_amdgcn_mfma_f32_16x16x32_bf16(\
                    af[m], bg[n], acc[(MH) * 4 + m][n], 0, 0, 0);              \
        __builtin_amdgcn_s_setprio(0);                                         \
    }

template <int EPI, typename CT>
__global__ __launch_bounds__(512, 1) void gemm256(
    const bf16* __restrict__ A, const bf16* __restrict__ BT, CT* __restrict__ C,
    const float* __restrict__ bias, const float* __restrict__ resid,
    int M, int N, int K)
{
    __shared__ bf16 L0[32768];
    __shared__ bf16 L1[32768];
    const int t    = threadIdx.x;
    const int lane = t & 63;
    const int w    = t >> 6;
    const int la   = lane & 15;
    const int g    = lane >> 4;

    const int nx  = gridDim.x;
    const int nwg = nx * gridDim.y;
    const int lin = blockIdx.y * nx + blockIdx.x;
    const int swzb = (lin & 7) * (nwg >> 3) + (lin >> 3);
    const int by  = swzb / nx, bx = swzb - by * nx;

    const int m0 = by * 256, n0 = bx * 256;
    const int wm = w >> 2, wn = w & 3;

    f32x4 acc[8][4];
    #pragma unroll
    for (int m = 0; m < 8; m++)
        #pragma unroll
        for (int n = 0; n < 4; n++) {
            f32x4 z4 = {0.f, 0.f, 0.f, 0.f};
            acc[m][n] = z4;
        }

    const int nt = K >> 6;

    const int rq = w * 8 + (lane >> 3);
    const int c8 = ((lane & 7) ^ (lane >> 3)) * 8;
    auto stageQ = [&](int kt_, int q, bf16* Lb) {
        const size_t k0 = (size_t)kt_ << 6;
        gld_lds16(A  + (size_t)(m0 + q * 64 + rq) * K + k0 + c8,
                  Lb + q * 4096 + w * 512);
        gld_lds16(BT + (size_t)(n0 + q * 64 + rq) * K + k0 + c8,
                  Lb + 16384 + q * 4096 + w * 512);
    };

    const int sw0 = (g ^ (la & 7)) << 4;
    const int sw1 = ((4 + g) ^ (la & 7)) << 4;
    const int aoff = (wm * 128 + la) * 128;
    const int boff = 32768 + (wn * 64 + la) * 128;
    const char* a0k0 = (const char*)L0 + aoff + sw0;
    const char* a0k1 = (const char*)L0 + aoff + sw1;
    const char* b0k0 = (const char*)L0 + boff + sw0;
    const char* b0k1 = (const char*)L0 + boff + sw1;
    const char* a1k0 = (const char*)L1 + aoff + sw0;
    const char* a1k1 = (const char*)L1 + aoff + sw1;
    const char* b1k0 = (const char*)L1 + boff + sw0;
    const char* b1k1 = (const char*)L1 + boff + sw1;

    stageQ(0, 0, L0); stageQ(0, 1, L0); stageQ(0, 2, L0); stageQ(0, 3, L0);

    bf16x8 af[4], bg[4];
    for (int tt = 0; tt < nt; tt += 2) {
        const bool more = (tt + 2 < nt);
        __builtin_amdgcn_s_barrier();
        stageQ(tt + 1, 0, L1);
        asm volatile("s_waitcnt vmcnt(2)" ::: "memory");
        __builtin_amdgcn_sched_barrier(0);
        __builtin_amdgcn_s_barrier();
        GP(a0k0, b0k0, 0, true);
        __builtin_amdgcn_s_barrier();
        stageQ(tt + 1, 1, L1);
        GP(a0k0, b0k0, 1, false);
        __builtin_amdgcn_s_barrier();
        stageQ(tt + 1, 2, L1);
        GP(a0k1, b0k1, 0, true);
        __builtin_amdgcn_s_barrier();
        stageQ(tt + 1, 3, L1);
        GP(a0k1, b0k1, 1, false);
        __builtin_amdgcn_s_barrier();
        if (more) {
            stageQ(tt + 2, 0, L0);
            asm volatile("s_waitcnt vmcnt(2)" ::: "memory");
        } else {
            asm volatile("s_waitcnt vmcnt(0)" ::: "memory");
        }
        __builtin_amdgcn_sched_barrier(0);
        __builtin_amdgcn_s_barrier();
        GP(a1k0, b1k0, 0, true);
        __builtin_amdgcn_s_barrier();
        if (more) stageQ(tt + 2, 1, L0);
        GP(a1k0, b1k0, 1, false);
        __builtin_amdgcn_s_barrier();
        if (more) stageQ(tt + 2, 2, L0);
        GP(a1k1, b1k1, 0, true);
        __builtin_amdgcn_s_barrier();
        if (more) stageQ(tt + 2, 3, L0);
        GP(a1k1, b1k1, 1, false);
    }

    const int row0 = m0 + wm * 128 + g * 4;
    const int col0 = n0 + wn * 64 + la;
    float bj[4];
    if (EPI >= 2) {
        #pragma unroll
        for (int n = 0; n < 4; n++) bj[n] = bias[col0 + n * 16];
    }
    #pragma unroll
    for (int m = 0; m < 8; m++) {
        #pragma unroll
        for (int r = 0; r < 4; r++) {
            const int row = row0 + m * 16 + r;
            #pragma unroll
            for (int n = 0; n < 4; n++) {
                const int col = col0 + n * 16;
                float v = acc[m][n][r];
                if (EPI >= 2) v += bj[n];
                if (EPI == 2) v = 0.5f * v * (1.0f + erff(v * 0.70710678118654752f));
                if (EPI == 3) v += resid[(size_t)row * N + col];
                C[(size_t)row * N + col] = from_f<CT>(v);
            }
        }
    }
}

// ---------------------------------------------------------------------------
// 128x128-tile GEMM (round-10/16 benched) — short-K GEMMs (QKV, Wo)
// ---------------------------------------------------------------------------
template <int EPI, typename CT>
__global__ __launch_bounds__(256, 4) void gemm128(
    const bf16* __restrict__ A, const bf16* __restrict__ BT, CT* __restrict__ C,
    const float* __restrict__ bias, const float* __restrict__ resid,
    int M, int N, int K)
{
    __shared__ bf16 L0[8192];
    __shared__ bf16 L1[8192];
    const int t    = threadIdx.x;
    const int lane = t & 63;
    const int w    = t >> 6;
    const int la   = lane & 15;
    const int g    = lane >> 4;

    const int nx  = gridDim.x;
    const int nwg = nx * gridDim.y;
    const int lin = blockIdx.y * nx + blockIdx.x;
    const int swzb = (lin & 7) * (nwg >> 3) + (lin >> 3);
    const int by  = swzb / nx, bx = swzb - by * nx;

    const int m0 = by * 128, n0 = bx * 128;
    const int wm = w >> 1, wn = w & 1;

    f32x4 acc[4][4];
    #pragma unroll
    for (int m = 0; m < 4; m++)
        #pragma unroll
        for (int n = 0; n < 4; n++) {
            f32x4 z4 = {0.f, 0.f, 0.f, 0.f};
            acc[m][n] = z4;
        }

    const int nt = K >> 5;

    const int r16 = lane >> 2;
    const int c4  = ((lane & 3) ^ ((lane >> 3) & 3)) * 8;
    auto stage = [&](int kt_, bf16* Lb) {
        const size_t k0 = (size_t)kt_ << 5;
        #pragma unroll
        for (int j = 0; j < 2; j++) {
            const int row = (j * 4 + w) * 16 + r16;
            gld_lds16(A  + (size_t)(m0 + row) * K + k0 + c4,
                      Lb + (j * 4 + w) * 512);
            gld_lds16(BT + (size_t)(n0 + row) * K + k0 + c4,
                      Lb + 4096 + (j * 4 + w) * 512);
        }
    };

    const int swz = ((g ^ ((la >> 1) & 3)) << 4);
    const char* bA0 = (const char*)L0 + (wm * 64 + la) * 64 + swz;
    const char* bB0 = (const char*)L0 + 8192 + (wn * 64 + la) * 64 + swz;
    const char* bA1 = (const char*)L1 + (wm * 64 + la) * 64 + swz;
    const char* bB1 = (const char*)L1 + 8192 + (wn * 64 + la) * 64 + swz;

    auto comp = [&](const char* bA, const char* bB) {
        bf16x8 af[4], bg[4];
        #pragma unroll
        for (int n = 0; n < 4; n++) bg[n] = *(const bf16x8*)(bB + n * 1024);
        #pragma unroll
        for (int m = 0; m < 4; m++) af[m] = *(const bf16x8*)(bA + m * 1024);
        #pragma unroll
        for (int m = 0; m < 4; m++)
            #pragma unroll
            for (int n = 0; n < 4; n++)
                acc[m][n] = __builtin_amdgcn_mfma_f32_16x16x32_bf16(
                    af[m], bg[n], acc[m][n], 0, 0, 0);
    };

    stage(0, L0);
    VMC(0);
    __builtin_amdgcn_sched_barrier(0);
    __builtin_amdgcn_s_barrier();

    for (int tt = 0; tt < nt; tt += 2) {
        const bool more = (tt + 2 < nt);
        stage(tt + 1, L1);
        comp(bA0, bB0);
        VMC(0);
        __builtin_amdgcn_sched_barrier(0);
        __builtin_amdgcn_s_barrier();
        if (more) stage(tt + 2, L0);
        comp(bA1, bB1);
        if (more) {
            VMC(0);
            __builtin_amdgcn_sched_barrier(0);
            __builtin_amdgcn_s_barrier();
        }
    }

    const int row0 = m0 + wm * 64 + g * 4;
    const int col0 = n0 + wn * 64 + la;
    float bj[4];
    if (EPI >= 2) {
        #pragma unroll
        for (int n = 0; n < 4; n++) bj[n] = bias[col0 + n * 16];
    }
    #pragma unroll
    for (int m = 0; m < 4; m++) {
        #pragma unroll
        for (int r = 0; r < 4; r++) {
            const int row = row0 + m * 16 + r;
            #pragma unroll
            for (int n = 0; n < 4; n++) {
                const int col = col0 + n * 16;
                float v = acc[m][n][r];
                if (EPI >= 2) v += bj[n];
                if (EPI == 2) v = 0.5f * v * (1.0f + erff(v * 0.70710678118654752f));
                if (EPI == 3) v += resid[(size_t)row * N + col];
                C[(size_t)row * N + col] = from_f<CT>(v);
            }
        }
    }
}

// ---------------------------------------------------------------------------
// Fused prologue: x->bf16 cast AND all weight transpose-casts in ONE launch.
// ---------------------------------------------------------------------------
__global__ __launch_bounds__(256) void prep_k(
    const float* __restrict__ X, bf16* __restrict__ Xb,
    const float* __restrict__ Wq, const float* __restrict__ Wk,
    const float* __restrict__ Wv, const float* __restrict__ Wo,
    const float* __restrict__ W1, const float* __restrict__ W2,
    bf16* __restrict__ WqkvT, bf16* __restrict__ WoT,
    bf16* __restrict__ W1T, bf16* __restrict__ W2T)
{
    const int fb0 = blockIdx.x;
    if (fb0 < 16384) {
        size_t i = ((size_t)fb0 * 256 + threadIdx.x) * 4;
        float4 v = *(const float4*)(X + i);
        union { bf16 b[4]; unsigned long long u; } o;
        o.b[0] = __float2bfloat16(v.x);
        o.b[1] = __float2bfloat16(v.y);
        o.b[2] = __float2bfloat16(v.z);
        o.b[3] = __float2bfloat16(v.w);
        *(unsigned long long*)(Xb + i) = o.u;
        return;
    }
    __shared__ float tile[32][33];
    const int fb = fb0 - 16384;
    const float* W; bf16* WT; int K, N, n0, k0;
    if (fb < 1536) {
        const int z = fb / 512, idx = fb - z * 512;
        W  = (z == 0) ? Wq : (z == 1) ? Wk : Wv;
        WT = WqkvT + (size_t)z * 512 * 1024;
        K = 1024; N = 512;
        n0 = (idx & 15) * 32; k0 = (idx >> 4) * 32;
    } else if (fb < 2048) {
        const int idx = fb - 1536;
        W = Wo; WT = WoT; K = 512; N = 1024;
        n0 = (idx & 31) * 32; k0 = (idx >> 5) * 32;
    } else if (fb < 6144) {
        const int idx = fb - 2048;
        W = W1; WT = W1T; K = 1024; N = 4096;
        n0 = (idx & 127) * 32; k0 = (idx >> 7) * 32;
    } else {
        const int idx = fb - 6144;
        W = W2; WT = W2T; K = 4096; N = 1024;
        n0 = (idx & 31) * 32; k0 = (idx >> 5) * 32;
    }
    const int tx = threadIdx.x & 31, ty = threadIdx.x >> 5;
    #pragma unroll
    for (int i = 0; i < 32; i += 8)
        tile[ty + i][tx] = W[(size_t)(k0 + ty + i) * N + n0 + tx];
    __syncthreads();
    #pragma unroll
    for (int i = 0; i < 32; i += 8)
        WT[(size_t)(n0 + ty + i) * K + k0 + tx] = __float2bfloat16(tile[tx][ty + i]);
}

// V (stride LDQKV) -> Vt [ (b*8+h)*64+dv ][ s ]
__global__ __launch_bounds__(256) void vtrans_k(const bf16* __restrict__ V,
                                                bf16* __restrict__ Vt)
{
    __shared__ bf16 t_[64 * 64];
    const int t = threadIdx.x;
    const int sblk = blockIdx.x & 127;
    const int b = blockIdx.x >> 7;
    const int h = blockIdx.y;
    const bf16* src = V + ((size_t)b * S_ + sblk * 64) * LDQKV + h * 64;
    #pragma unroll
    for (int k = 0; k < 2; k++) {
        int e = t + k * 256;
        int r = e >> 3, c8 = (e & 7) * 8;
        *(bf16x8*)&t_[r * 64 + c8] = *(const bf16x8*)&src[(size_t)r * LDQKV + c8];
    }
    __syncthreads();
    const int dv = t & 63, s0 = (t >> 6) * 16;
    bf16* dst = Vt + ((size_t)(b * 8 + h) * 64 + dv) * (size_t)S_ + sblk * 64 + s0;
    bvec o0, o1;
    #pragma unroll
    for (int i = 0; i < 8; i++) {
        o0.e[i] = t_[(s0 + i) * 64 + dv];
        o1.e[i] = t_[(s0 + 8 + i) * 64 + dv];
    }
    *(bf16x8*)dst = o0.v;
    *(bf16x8*)(dst + 8) = o1.v;
}

// ---------------------------------------------------------------------------
// Per-(segment, 1/16-chunk) partial memory; grid (NSEG_*16, 16)
// ---------------------------------------------------------------------------
__global__ __launch_bounds__(256) void memseg_k(
    const bf16* __restrict__ Kg, const bf16* __restrict__ Vg,
    float* __restrict__ MP, float* __restrict__ ZP)
{
    __shared__ float Ks[64][65];
    __shared__ float Vs[64][65];
    const int t = threadIdx.x, tx = t & 15, ty = t >> 4;
    const int sb = blockIdx.x;
    const int seg = sb >> 4, bh = sb & 15;
    const int b = bh >> 3, h = bh & 7;
    const int chunk = blockIdx.y;
    const size_t base = ((size_t)b * S_ + (size_t)seg * SEG_ + (size_t)chunk * 128) * LDQKV + h * 64;

    float acc[4][4] = {};
    float zacc[4]   = {};
    for (int st = 0; st < 2; st++) {
        #pragma unroll
        for (int kk = 0; kk < 2; kk++) {
            int e = t + kk * 256;
            int r = e >> 3, c8 = (e & 7) * 8;
            size_t go = base + ((size_t)st * 64 + r) * LDQKV + c8;
            bvec kv_, vv_;
            kv_.v = *(const bf16x8*)&Kg[go];
            vv_.v = *(const bf16x8*)&Vg[go];
            #pragma unroll
            for (int i = 0; i < 8; i++) {
                Ks[r][c8 + i] = elu1(__bfloat162float(kv_.e[i]));
                Vs[r][c8 + i] = __bfloat162float(vv_.e[i]);
            }
        }
        __syncthreads();
        for (int s = 0; s < 64; s++) {
            float a4[4], v4[4];
            #pragma unroll
            for (int i = 0; i < 4; i++) a4[i] = Ks[s][ty * 4 + i];
            #pragma unroll
            for (int j = 0; j < 4; j++) v4[j] = Vs[s][tx * 4 + j];
            #pragma unroll
            for (int i = 0; i < 4; i++)
                #pragma unroll
                for (int j = 0; j < 4; j++)
                    acc[i][j] += a4[i] * v4[j];
        }
        #pragma unroll
        for (int ii = 0; ii < 4; ii++) {
            int s = tx + ii * 16;
            #pragma unroll
            for (int i = 0; i < 4; i++) zacc[i] += Ks[s][ty * 4 + i];
        }
        __syncthreads();
    }
    const int slot = (seg * 16 + chunk) * 16 + bh;
    #pragma unroll
    for (int i = 0; i < 4; i++)
        #pragma unroll
        for (int j = 0; j < 4; j++)
            MP[(size_t)slot * 4096 + (ty * 4 + i) * 64 + tx * 4 + j] = acc[i][j];
    #pragma unroll
    for (int i = 0; i < 4; i++) {
        float zz = zacc[i];
        #pragma unroll
        for (int mk = 1; mk < 16; mk <<= 1) zz += __shfl_xor(zz, mk);
        if (tx == 0) ZP[slot * 64 + ty * 4 + i] = zz;
    }
}

// exclusive prefix over 64 (seg,chunk) slots; grid (16 bh, 16 e-groups)
__global__ __launch_bounds__(256) void prefix_k(
    const float* __restrict__ MP, const float* __restrict__ ZP,
    bf16* __restrict__ MST, float* __restrict__ ZS)
{
    const int bh = blockIdx.x;
    const int e  = blockIdx.y * 256 + threadIdx.x;
    const int dk = e >> 6, dv = e & 63;
    float s = 0.f;
    for (int si = 0; si < 64; si++) {
        if ((si & 15) == 0)
            MST[(size_t)((si >> 4) * 16 + bh) * 4096 + dv * 64 + dk] = __float2bfloat16(s);
        s += MP[(size_t)(si * 16 + bh) * 4096 + e];
    }
    if (blockIdx.y == 0 && threadIdx.x < 64) {
        const int dz = threadIdx.x;
        float z = 1.0f / DK_;
        for (int si = 0; si < 64; si++) {
            if ((si & 15) == 0) ZS[((si >> 4) * 16 + bh) * 64 + dz] = z;
            z += ZP[(si * 16 + bh) * 64 + dz];
        }
    }
}

// ---------------------------------------------------------------------------
// attn helpers
// ---------------------------------------------------------------------------
template <int NG>
__device__ __forceinline__ void stageT(const bf16* gsrc, size_t stride, bf16* lds,
                                       int wave, int lane)
{
    #pragma unroll
    for (int ii = 0; ii < NG; ii++) {
        int i = wave * NG + ii;
        gld_lds16(gsrc + (size_t)(8 * i + (lane >> 3)) * stride
                        + (size_t)(((lane & 7) ^ (lane >> 3)) * 8),
                  lds + i * 512);
    }
}

__device__ __forceinline__ bf16x8 ldsw128(const bf16* base, int row, int colE)
{
    int off = row * 128 + ((colE * 2) ^ ((row & 7) << 4));
    return *(const bf16x8*)((const char*)base + off);
}

// ---------------------------------------------------------------------------
// MFMA flash attention (round-16 benched — NO setprio; reverted)
// ---------------------------------------------------------------------------
__global__ __launch_bounds__(256) void attn_k(
    const bf16* __restrict__ Qg, const bf16* __restrict__ Kg, const bf16* __restrict__ Vt,
    const bf16* __restrict__ MsT, const float* __restrict__ ZS,
    const float* __restrict__ betas, bf16* __restrict__ att)
{
    __shared__ bf16 KT[2][4096];
    __shared__ bf16 VTs[2][4096];
    __shared__ bf16 QP[8192];
    __shared__ float Zsm[64];

    const int t    = threadIdx.x;
    const int lane = t & 63;
    const int w    = t >> 6;
    const int la   = lane & 15;
    const int g    = lane >> 4;
    const int qt   = (int)gridDim.x - 1 - (int)blockIdx.x;
    const int bh   = blockIdx.y;
    const int seg  = blockIdx.z;
    const int b    = bh >> 3, h = bh & 7;

    const size_t srow = (size_t)b * S_ + (size_t)seg * SEG_;
    const bf16* qp  = Qg + (srow + (size_t)qt * 128) * LDQKV + h * 64;
    const bf16* kp  = Kg + srow * LDQKV + h * 64;
    const bf16* vtp = Vt + (size_t)bh * 64 * (size_t)S_ + (size_t)seg * SEG_;

    stageT<4>(qp, LDQKV, QP, w, lane);
    stageT<2>(kp, LDQKV, KT[0], w, lane);
    stageT<2>(vtp, S_, VTs[0], w, lane);
    if (t < 64) Zsm[t] = ZS[(seg * 16 + bh) * 64 + t];
    __syncthreads();

    bf16x8 aq[2][2];
    #pragma unroll
    for (int st = 0; st < 2; st++)
        #pragma unroll
        for (int s = 0; s < 2; s++)
            aq[st][s] = ldsw128(QP, w * 32 + st * 16 + la, s * 32 + g * 8);

    float m_[2] = {-1e30f, -1e30f};
    float l_[2] = {0.f, 0.f};
    f32x4 Oa[2][4];
    #pragma unroll
    for (int st = 0; st < 2; st++)
        #pragma unroll
        for (int j = 0; j < 4; j++) { f32x4 z4 = {0.f,0.f,0.f,0.f}; Oa[st][j] = z4; }

    const int jtmax = 2 * qt + 1;
    int cur = 0;
    for (int jt = 0; jt <= jtmax; jt++, cur ^= 1) {
        if (jt < jtmax) {
            stageT<2>(kp + (size_t)(jt + 1) * 64 * LDQKV, LDQKV, KT[cur ^ 1], w, lane);
            stageT<2>(vtp + (size_t)(jt + 1) * 64, S_, VTs[cur ^ 1], w, lane);
        }

        bf16x8 kf[2][4];
        #pragma unroll
        for (int s = 0; s < 2; s++)
            #pragma unroll
            for (int j = 0; j < 4; j++)
                kf[s][j] = ldsw128(KT[cur], j * 16 + la, s * 32 + g * 8);

        const int jtkv = jt * 64;
        #pragma unroll
        for (int st = 0; st < 2; st++) {
            f32x4 sc[4];
            #pragma unroll
            for (int j = 0; j < 4; j++) { f32x4 z4 = {0.f,0.f,0.f,0.f}; sc[j] = z4; }
            #pragma unroll
            for (int j = 0; j < 4; j++) {
                sc[j] = __builtin_amdgcn_mfma_f32_16x16x32_bf16(kf[0][j], aq[st][0], sc[j], 0, 0, 0);
                sc[j] = __builtin_amdgcn_mfma_f32_16x16x32_bf16(kf[1][j], aq[st][1], sc[j], 0, 0, 0);
            }

            const int q_abs = qt * 128 + w * 32 + st * 16 + la;
            float sv[4][4];
            float mx = -1e30f;
            #pragma unroll
            for (int j = 0; j < 4; j++)
                #pragma unroll
                for (int r = 0; r < 4; r++) {
                    float v = sc[j][r] * 0.125f;
                    int kv = jtkv + j * 16 + g * 4 + r;
                    v = (kv <= q_abs) ? v : -1e30f;
                    sv[j][r] = v;
                    mx = fmaxf(mx, v);
                }
            mx = fmaxf(mx, __shfl_xor(mx, 16));
            mx = fmaxf(mx, __shfl_xor(mx, 32));
            float mnew = fmaxf(m_[st], mx);
            float corr = __expf(m_[st] - mnew);
            float rs = 0.f;
            #pragma unroll
            for (int j = 0; j < 4; j++)
                #pragma unroll
                for (int r = 0; r < 4; r++) {
                    float p = __expf(sv[j][r] - mnew);
                    sv[j][r] = p;
                    rs += p;
                }
            rs += __shfl_xor(rs, 16);
            rs += __shfl_xor(rs, 32);
            l_[st] = l_[st] * corr + rs;
            m_[st] = mnew;

            const int R = w * 32 + st * 16 + la;
            #pragma unroll
            for (int j = 0; j < 4; j++) {
                union { bf16 e[4]; uint2 u; } pk;
                #pragma unroll
                for (int r = 0; r < 4; r++) pk.e[r] = __float2bfloat16(sv[j][r]);
                int off = R * 128 + ((j * 32 + g * 8) ^ ((la & 7) << 4));
                *(uint2*)((char*)QP + off) = pk.u;
            }

            #pragma unroll
            for (int r = 0; r < 4; r++) {
                float corr_r = __shfl(corr, (lane & 48) | (g * 4 + r));
                #pragma unroll
                for (int j = 0; j < 4; j++) Oa[st][j][r] *= corr_r;
            }
        }

        asm volatile("s_waitcnt lgkmcnt(0)" ::: "memory");
        __builtin_amdgcn_sched_barrier(0);

        bf16x8 bv[2][4];
        #pragma unroll
        for (int s = 0; s < 2; s++)
            #pragma unroll
            for (int j = 0; j < 4; j++)
                bv[s][j] = ldsw128(VTs[cur], j * 16 + la, s * 32 + g * 8);
        #pragma unroll
        for (int st = 0; st < 2; st++) {
            bf16x8 ap0 = ldsw128(QP, w * 32 + st * 16 + la, g * 8);
            bf16x8 ap1 = ldsw128(QP, w * 32 + st * 16 + la, 32 + g * 8);
            #pragma unroll
            for (int j = 0; j < 4; j++) {
                Oa[st][j] = __builtin_amdgcn_mfma_f32_16x16x32_bf16(ap0, bv[0][j], Oa[st][j], 0, 0, 0);
                Oa[st][j] = __builtin_amdgcn_mfma_f32_16x16x32_bf16(ap1, bv[1][j], Oa[st][j], 0, 0, 0);
            }
        }
        __syncthreads();
    }

    // ---- retrieval ----
    stageT<2>(MsT + (size_t)(seg * 16 + bh) * 4096, 64, KT[0], w, lane);
    __syncthreads();

    bf16x8 sq[2][2];
    float den[2] = {0.f, 0.f};
    #pragma unroll
    for (int st = 0; st < 2; st++) {
        #pragma unroll
        for (int s = 0; s < 2; s++) {
            bvec in, outv;
            in.v = aq[st][s];
            #pragma unroll
            for (int e = 0; e < 8; e++) {
                float f = elu1(__bfloat162float(in.e[e]));
                outv.e[e] = __float2bfloat16(f);
                den[st] += f * Zsm[s * 32 + 8 * g + e];
            }
            sq[st][s] = outv.v;
        }
        den[st] += __shfl_xor(den[st], 16);
        den[st] += __shfl_xor(den[st], 32);
    }

    bf16x8 bm[2][4];
    #pragma unroll
    for (int s = 0; s < 2; s++)
        #pragma unroll
        for (int j = 0; j < 4; j++)
            bm[s][j] = ldsw128(KT[0], j * 16 + la, s * 32 + g * 8);

    float gate[4];
    #pragma unroll
    for (int j = 0; j < 4; j++)
        gate[j] = 1.f / (1.f + __expf(-betas[h * 64 + j * 16 + la]));

    #pragma unroll
    for (int st = 0; st < 2; st++) {
        f32x4 num[4];
        #pragma unroll
        for (int j = 0; j < 4; j++) { f32x4 z4 = {0.f,0.f,0.f,0.f}; num[j] = z4; }
        #pragma unroll
        for (int j = 0; j < 4; j++) {
            num[j] = __builtin_amdgcn_mfma_f32_16x16x32_bf16(sq[st][0], bm[0][j], num[j], 0, 0, 0);
            num[j] = __builtin_amdgcn_mfma_f32_16x16x32_bf16(sq[st][1], bm[1][j], num[j], 0, 0, 0);
        }
        #pragma unroll
        for (int r = 0; r < 4; r++) {
            float den_r = __shfl(den[st], (lane & 48) | (g * 4 + r));
            float l_r   = __shfl(l_[st],  (lane & 48) | (g * 4 + r));
            float linv  = 1.f / l_r;
            float dinv  = 1.f / den_r;
            size_t orow = srow + (size_t)qt * 128 + w * 32 + st * 16 + g * 4 + r;
            #pragma unroll
            for (int j = 0; j < 4; j++) {
                float am = num[j][r] * dinv;
                float ad = Oa[st][j][r] * linv;
                att[orow * 512 + h * 64 + j * 16 + la] =
                    __float2bfloat16(gate[j] * am + (1.f - gate[j]) * ad);
            }
        }
    }
}

// ---------------------------------------------------------------------------
// LayerNorm reading bf16 y, f32 out
// ---------------------------------------------------------------------------
__global__ __launch_bounds__(256) void lnb_k(
    const bf16* __restrict__ Y, const float* __restrict__ g,
    const float* __restrict__ bta, float* __restrict__ out)
{
    const int row = blockIdx.x;
    const bf16* yp = Y + (size_t)row * D_;
    const int t = threadIdx.x;
    float v[4];
    float s = 0.f, s2 = 0.f;
    {
        union { bf16 e[4]; uint2 u; } ld;
        ld.u = *(const uint2*)(yp + t * 4);
        #pragma unroll
        for (int i = 0; i < 4; i++) {
            v[i] = __bfloat162float(ld.e[i]);
            s += v[i]; s2 += v[i] * v[i];
        }
    }
    #pragma unroll
    for (int mk = 1; mk < 64; mk <<= 1) {
        s  += __shfl_xor(s, mk);
        s2 += __shfl_xor(s2, mk);
    }
    __shared__ float ss[4], ss2[4];
    int w = t >> 6;
    if ((t & 63) == 0) { ss[w] = s; ss2[w] = s2; }
    __syncthreads();
    s  = ss[0] + ss[1] + ss[2] + ss[3];
    s2 = ss2[0] + ss2[1] + ss2[2] + ss2[3];
    float mu   = s / D_;
    float var  = s2 / D_ - mu * mu;
    float rstd = rsqrtf(var + EPS_);
    #pragma unroll
    for (int i = 0; i < 4; i++) {
        int c = t * 4 + i;
        out[(size_t)row * D_ + c] = (v[i] - mu) * rstd * g[c] + bta[c];
    }
}

// ---------------------------------------------------------------------------
extern "C" void kernel_launch(void* const* d_in, const int* in_sizes, int n_in,
                              void* d_out, int out_size, void* d_ws, size_t ws_size,
                              hipStream_t stream)
{
    const float* x     = (const float*)d_in[0];
    const float* Wq    = (const float*)d_in[1];
    const float* Wk    = (const float*)d_in[2];
    const float* Wv    = (const float*)d_in[3];
    const float* Wo    = (const float*)d_in[4];
    const float* betas = (const float*)d_in[5];
    const float* W1    = (const float*)d_in[6];
    const float* b1    = (const float*)d_in[7];
    const float* W2    = (const float*)d_in[8];
    const float* b2    = (const float*)d_in[9];
    const float* lng   = (const float*)d_in[10];
    const float* lnb   = (const float*)d_in[11];
    float* out = (float*)d_out;

    const int M = B_ * S_;                    // 16384
    char* base = (char*)d_ws;
    const size_t MB = 1024 * 1024;

    // Liveness-safe layout (round-13/16 benched):
    bf16*  Ab    = (bf16*)(base);
    bf16*  Yb    = (bf16*)(base);             // aliases Ab; Ab dead after W1
    bf16*  Hb    = (bf16*)(base + 32 * MB);
    bf16*  Xbf   = (bf16*)(base + 32 * MB);
    bf16*  QKV   = (bf16*)(base + 64 * MB);   // [M][1536]
    bf16*  Vt    = (bf16*)(base + 112 * MB);
    bf16*  ATT   = (bf16*)(base + 128 * MB);  // [M][512]
    bf16*  WqkvT = (bf16*)(base + 160 * MB);  // 3MB
    bf16*  WoT   = (bf16*)(base + 163 * MB);  // 1MB
    bf16*  W1T   = (bf16*)(base + 164 * MB);  // 8MB
    bf16*  W2T   = (bf16*)(base + 172 * MB);  // 8MB
    float* MP    = (float*)(base + 180 * MB); // 16MB (180-196)
    bf16*  MST   = (bf16*)(base + 196 * MB);  // 512KB
    float* ZP    = (float*)(base + 196 * MB + 512 * 1024);   // 256KB
    float* ZS    = (float*)(base + 196 * MB + 768 * 1024);

    dim3 blk(256);
    dim3 blk512(512);

    // fused prologue: castx + all weight transpose-casts
    prep_k<<<dim3(16384 + 10240), blk, 0, stream>>>(
        x, Xbf, Wq, Wk, Wv, Wo, W1, W2, WqkvT, WoT, W1T, W2T);

    // fused QKV projection (short K -> gemm128)
    gemm128<0, bf16><<<dim3(1536 / 128, M / 128), blk, 0, stream>>>(
        Xbf, WqkvT, QKV, nullptr, nullptr, M, 1536, 1024);

    vtrans_k<<<dim3(256, 8), blk, 0, stream>>>(QKV + 1024, Vt);

    memseg_k<<<dim3(NSEG_ * 16, 16), blk, 0, stream>>>(QKV + 512, QKV + 1024, MP, ZP);
    prefix_k<<<dim3(16, 16), blk, 0, stream>>>(MP, ZP, MST, ZS);

    attn_k<<<dim3(SEG_ / 128, 16, NSEG_), blk, 0, stream>>>(
        QKV, QKV + 512, Vt, MST, ZS, betas, ATT);

    // output projection (short K -> gemm128)
    gemm128<0, bf16><<<dim3(1024 / 128, M / 128), blk, 0, stream>>>(
        ATT, WoT, Ab, nullptr, nullptr, M, 1024, 512);
    // FFN (big K -> gemm256, benched best)
    gemm256<2, bf16><<<dim3(4096 / 256, M / 256), blk512, 0, stream>>>(
        Ab, W1T, Hb, b1, nullptr, M, 4096, 1024);
    gemm256<3, bf16><<<dim3(1024 / 256, M / 256), blk512, 0, stream>>>(
        Hb, W2T, Yb, b2, x, M, 1024, 4096);

    lnb_k<<<dim3(M), blk, 0, stream>>>(Yb, lng, lnb, out);
}